// Round 6
// baseline (515.369 us; speedup 1.0000x reference)
//
#include <hip/hip_runtime.h>

// ---------------------------------------------------------------------------
// DCGRU cell on MI355X — fused single-kernel, v2 hop structure (fixed).
// B=32, N=1024, C_IN=2, H=32, S=2, K=2, NUM_MAT=5, c_cat=34.
//
// ws layout (pathF): [Apk 128MB][H1 15MB][H2 15MB][ubuf 4MB][bar 256B]
// Apk: A bf16 packed in MFMA-fragment order, matrix index mat = b*2+s
//   (memory order of supports[B][S][N][N]):
//   chunk t = ((((mat*64 + rt)*16 + kt)*2 + kb)*64 + lane), 16B per chunk
//   chunk holds A[rt*16 + (lane&15)][kt*64 + kb*32 + (lane>>4)*4 + {0..3, 16..19}]
// H buffer: per b: 5 slots x 3 ct x [16 ch][1024 n] bf16; ch 34..47 zero pad.
// Output: d_out = (outputs, outputs), each 1,048,576 fp32.
//
// Hop phase: whole X panel (48ch x 1024k = 96 KB) staged to LDS once
// (pre-swizzled source -> conflict-limited reads), then barrier-free k-loop:
// A frags as coalesced 16B/lane global loads (L3-resident), 6 ds_read_b64 +
// 6 MFMA per (kt,kb). Grid 256 x 512thr, 96 KB LDS, 1 block/CU.
// ---------------------------------------------------------------------------

#define NN   1024
#define HB   245760
#define SUBT 16384
#define OUTCOPY 1048576

typedef float  f32x4  __attribute__((ext_vector_type(4)));
typedef short  s16x4  __attribute__((ext_vector_type(4)));
typedef short  s16x8  __attribute__((ext_vector_type(8)));
typedef __bf16 bf16x8 __attribute__((ext_vector_type(8)));
typedef unsigned int u32x4 __attribute__((ext_vector_type(4)));

#define GAS __attribute__((address_space(1)))
#define LAS __attribute__((address_space(3)))

__device__ __forceinline__ unsigned short f32_bf16(float f) {
  unsigned int u = __float_as_uint(f);
  u += 0x7FFFu + ((u >> 16) & 1u);
  return (unsigned short)(u >> 16);
}
__device__ __forceinline__ float bf16_f32(unsigned short h) {
  return __uint_as_float(((unsigned int)h) << 16);
}
__device__ __forceinline__ void gload_lds16(const unsigned short* g, void* l) {
  __builtin_amdgcn_global_load_lds((const GAS void*)g, (LAS void*)l, 16, 0, 0);
}

// grid-wide spin barrier; monotonic counter (reset by hipMemsetAsync per call)
__device__ __forceinline__ void gbar(unsigned* bar, unsigned target) {
  __syncthreads();
  if (threadIdx.x == 0) {
    __threadfence();
    __hip_atomic_fetch_add(bar, 1u, __ATOMIC_RELAXED, __HIP_MEMORY_SCOPE_AGENT);
    unsigned v;
    do {
      __builtin_amdgcn_s_sleep(8);
      v = __hip_atomic_load(bar, __ATOMIC_RELAXED, __HIP_MEMORY_SCOPE_AGENT);
    } while (v < target);
    __threadfence();
  }
  __syncthreads();
}

// ---------------------------------------------------------------------------
// hop phase v2: Y = A @ X for tiles m0, m0+4 of one (b,s).
// ---------------------------------------------------------------------------
__device__ void hop_phase(const unsigned short* __restrict__ Apk,
                          const unsigned short* __restrict__ Hin,
                          unsigned short* __restrict__ Hout,
                          int bs, int m0, char* lds,
                          int si0, int si1, int so0, int so1) {
  const int tid  = threadIdx.x;
  const int wave = tid >> 6, lane = tid & 63;
  const int l15  = lane & 15, l4 = lane >> 4;
  const int b = bs & 31, s = bs >> 5;
  const int mat = b * 2 + s;              // memory-order matrix index (FIX)
  const int slot_in  = s ? si1 : si0;
  const int slot_out = s ? so1 : so0;

  const unsigned short* Xb = Hin  + (size_t)b * HB + (size_t)slot_in  * 3 * SUBT;
  unsigned short*       Yb = Hout + (size_t)b * HB + (size_t)slot_out * 3 * SUBT;

  // ---- stage X panel: 48 rows x 2048 B, 16B chunks swizzled c ^ ((ch&7)<<1)
#pragma unroll
  for (int it = 0; it < 12; ++it) {
    int q  = it * 512 + tid;            // 0..6143
    int ch = q >> 7, c = q & 127;
    int gx = c ^ ((ch & 7) << 1);
    const unsigned short* g = Xb + (ch >> 4) * SUBT + (ch & 15) * NN + gx * 8;
    gload_lds16(g, lds + (it * 512 + wave * 64) * 16);
  }
  __syncthreads();   // drain vmcnt(0) + barrier: X panel ready (read-only after)

  // ---- barrier-free k-loop over both strips ----
  const int rt0 = m0 * 8 + wave;                 // strip 0 row-tile
  const int rt1 = (m0 + 4) * 8 + wave;           // strip 1 row-tile
  const unsigned short* A0 = Apk + ((((size_t)mat * 64 + rt0) * 16) * 2) * 512 + lane * 8;
  const unsigned short* A1 = Apk + ((((size_t)mat * 64 + rt1) * 16) * 2) * 512 + lane * 8;

  f32x4 acc[2][3];
#pragma unroll
  for (int st = 0; st < 2; ++st)
#pragma unroll
    for (int nt = 0; nt < 3; ++nt)
#pragma unroll
      for (int e = 0; e < 4; ++e) acc[st][nt][e] = 0.f;

  const int swr = (l15 & 7) << 1;   // X row swizzle key
  const int sub8 = (l4 & 1) * 8;

#pragma unroll 4
  for (int kt = 0; kt < 16; ++kt) {
#pragma unroll
    for (int kb = 0; kb < 2; ++kb) {
      bf16x8 a0 = __builtin_bit_cast(bf16x8, *(const s16x8*)(A0 + (size_t)(kt * 2 + kb) * 512));
      bf16x8 a1 = __builtin_bit_cast(bf16x8, *(const s16x8*)(A1 + (size_t)(kt * 2 + kb) * 512));
      const int g16 = kt * 8 + kb * 4 + (l4 >> 1);
#pragma unroll
      for (int nt = 0; nt < 3; ++nt) {
        const char* rowb = lds + (nt * 16 + l15) * 2048;
        s16x8 tb;
        tb.lo = *(const s16x4*)(rowb + ((g16 ^ swr) << 4) + sub8);
        tb.hi = *(const s16x4*)(rowb + (((g16 + 2) ^ swr) << 4) + sub8);
        bf16x8 bfr = __builtin_bit_cast(bf16x8, tb);
        acc[0][nt] = __builtin_amdgcn_mfma_f32_16x16x32_bf16(a0, bfr, acc[0][nt], 0, 0, 0);
        acc[1][nt] = __builtin_amdgcn_mfma_f32_16x16x32_bf16(a1, bfr, acc[1][nt], 0, 0, 0);
      }
    }
  }

  // ---- epilogue: D layout col(n)=l15 (=ch), row(m)=l4*4+reg ----
#pragma unroll
  for (int st = 0; st < 2; ++st) {
    const int row0 = (m0 + st * 4) * 128 + wave * 16 + (l4 << 2);
#pragma unroll
    for (int nt = 0; nt < 3; ++nt) {
      int ch = nt * 16 + l15;
      s16x4 o;
      o.x = (short)f32_bf16(acc[st][nt][0]);
      o.y = (short)f32_bf16(acc[st][nt][1]);
      o.z = (short)f32_bf16(acc[st][nt][2]);
      o.w = (short)f32_bf16(acc[st][nt][3]);
      *(s16x4*)(Yb + (size_t)ch * NN + row0) = o;
    }
  }
}

// ---------------------------------------------------------------------------
// fused kernel
// ---------------------------------------------------------------------------
__global__ __launch_bounds__(512, 2)
void dcgru_fused(const float* __restrict__ inputs, const float* __restrict__ supports,
                 const float* __restrict__ states,
                 const float* __restrict__ W_ru, const float* __restrict__ b_ru,
                 const float* __restrict__ W_c,  const float* __restrict__ b_c,
                 float* __restrict__ out,
                 unsigned short* __restrict__ Apk,
                 unsigned short* __restrict__ H1, unsigned short* __restrict__ H2,
                 float* __restrict__ ubuf, unsigned* bar) {
  __shared__ u32x4 ldsv[6144];   // 96 KB: X panel
  char* lds = (char*)ldsv;

  const int tid = threadIdx.x;
  const int gid = blockIdx.x * 512 + tid;    // 0..131071

  // tile mapping: XCD-chunked
  const int x  = blockIdx.x & 7;
  const int j  = blockIdx.x >> 3;
  const int bs = x * 8 + (j >> 2);
  const int m0 = j & 3;

  // ---- P0: cvt supports -> Apk (fragment-packed bf16, NT reads) + pack x1 ----
  {
    // chunk t: lane=t&63, kb=(t>>6)&1, kt=(t>>7)&15, rt=(t>>11)&63, mat=t>>17
#pragma unroll 1
    for (int it = 0; it < 64; ++it) {
      int t = gid + it * 131072;
      int ln = t & 63;
      int kb = (t >> 6) & 1;
      int kt = (t >> 7) & 15;
      int rt = (t >> 11) & 63;
      int tmat = t >> 17;
      int row = rt * 16 + (ln & 15);
      int k0  = kt * 64 + kb * 32 + (ln >> 4) * 4;
      const float* src = supports + (size_t)tmat * NN * NN + (size_t)row * NN + k0;
      f32x4 vlo = __builtin_nontemporal_load((const f32x4*)src);
      f32x4 vhi = __builtin_nontemporal_load((const f32x4*)(src + 16));
      s16x8 o;
      o[0] = (short)f32_bf16(vlo[0]); o[1] = (short)f32_bf16(vlo[1]);
      o[2] = (short)f32_bf16(vlo[2]); o[3] = (short)f32_bf16(vlo[3]);
      o[4] = (short)f32_bf16(vhi[0]); o[5] = (short)f32_bf16(vhi[1]);
      o[6] = (short)f32_bf16(vhi[2]); o[7] = (short)f32_bf16(vhi[3]);
      *(s16x8*)(Apk + (size_t)t * 8) = o;
    }
    if (gid < 32768) {
      int b = gid >> 10, n = gid & 1023;
      unsigned short* xb = H1 + (size_t)b * HB;
      xb[0 * NN + n] = f32_bf16(inputs[gid * 2 + 0]);
      xb[1 * NN + n] = f32_bf16(inputs[gid * 2 + 1]);
#pragma unroll
      for (int o = 0; o < 32; ++o) {
        int ch = 2 + o;
        xb[(ch >> 4) * SUBT + (ch & 15) * NN + n] = f32_bf16(states[gid * 32 + o]);
      }
#pragma unroll
      for (int ch = 34; ch < 48; ++ch)
        xb[2 * SUBT + (ch & 15) * NN + n] = 0;
    }
  }
  gbar(bar, 256);

  // ---- P1, P2: hops on H1 ----
  hop_phase(Apk, H1, H1, bs, m0, lds, 0, 0, 1, 3);
  gbar(bar, 512);
  hop_phase(Apk, H1, H1, bs, m0, lds, 1, 3, 2, 4);
  gbar(bar, 768);

  // ---- P3: gate_ru ----
  {
#pragma unroll 1
    for (int rep = 0; rep < 2; ++rep) {
      int tau = gid + rep * 131072;
      int rw = tau >> 3, p = tau & 7;
      int b = rw >> 10, n = rw & 1023;
      const unsigned short* hb = H1 + (size_t)b * HB;
      float acc[8];
#pragma unroll
      for (int q = 0; q < 8; ++q) acc[q] = b_ru[p * 8 + q];
#pragma unroll 1
      for (int jj = 0; jj < 5; ++jj) {
        const unsigned short* sb = hb + jj * 3 * SUBT;
#pragma unroll 1
        for (int c = 0; c < 34; ++c) {
          float xv = bf16_f32(sb[(c >> 4) * SUBT + (c & 15) * NN + n]);
          const float* wr = W_ru + (jj * 34 + c) * 64 + p * 8;
          f32x4 w0 = *(const f32x4*)wr;
          f32x4 w1 = *(const f32x4*)(wr + 4);
#pragma unroll
          for (int q = 0; q < 4; ++q) acc[q]     = fmaf(xv, w0[q], acc[q]);
#pragma unroll
          for (int q = 0; q < 4; ++q) acc[4 + q] = fmaf(xv, w1[q], acc[4 + q]);
        }
      }
      unsigned short* xb = H2 + (size_t)b * HB;
      if (p < 4) {
#pragma unroll
        for (int q = 0; q < 8; ++q) {
          float r = 1.f / (1.f + __expf(-acc[q]));
          int o = p * 8 + q, ch = 2 + o;
          xb[(ch >> 4) * SUBT + (ch & 15) * NN + n] = f32_bf16(r * states[rw * 32 + o]);
        }
      } else {
        int mm = (p - 4) * 8;
#pragma unroll
        for (int q = 0; q < 8; ++q) {
          float u = 1.f / (1.f + __expf(-acc[q]));
          ubuf[((size_t)b * 32 + mm + q) * NN + n] = u;
        }
      }
      if (p == 4) { for (int ch = 34; ch < 41; ++ch) xb[2 * SUBT + (ch & 15) * NN + n] = 0; }
      if (p == 5) { for (int ch = 41; ch < 48; ++ch) xb[2 * SUBT + (ch & 15) * NN + n] = 0; }
      if (p == 6) {
        xb[0 * NN + n] = f32_bf16(inputs[rw * 2 + 0]);
        xb[1 * NN + n] = f32_bf16(inputs[rw * 2 + 1]);
      }
    }
  }
  gbar(bar, 1024);

  // ---- P4, P5: hops on H2 ----
  hop_phase(Apk, H2, H2, bs, m0, lds, 0, 0, 1, 3);
  gbar(bar, 1280);
  hop_phase(Apk, H2, H2, bs, m0, lds, 1, 3, 2, 4);
  gbar(bar, 1536);

  // ---- P6: gate_c + output ----
  {
#pragma unroll 1
    for (int rep = 0; rep < 2; ++rep) {
      int tau = gid + rep * 131072;
      int rw = tau >> 3, p = tau & 7;
      int b = rw >> 10, n = rw & 1023;
      const unsigned short* hb = H2 + (size_t)b * HB;
      float acc[4];
#pragma unroll
      for (int q = 0; q < 4; ++q) acc[q] = b_c[p * 4 + q];
#pragma unroll 1
      for (int jj = 0; jj < 5; ++jj) {
        const unsigned short* sb = hb + jj * 3 * SUBT;
#pragma unroll 1
        for (int c = 0; c < 34; ++c) {
          float xv = bf16_f32(sb[(c >> 4) * SUBT + (c & 15) * NN + n]);
          f32x4 w0 = *(const f32x4*)(W_c + (jj * 34 + c) * 32 + p * 4);
#pragma unroll
          for (int q = 0; q < 4; ++q) acc[q] = fmaf(xv, w0[q], acc[q]);
        }
      }
      f32x4 res;
#pragma unroll
      for (int q = 0; q < 4; ++q) {
        int o = p * 4 + q;
        float cc = tanhf(acc[q]);
        float u  = ubuf[((size_t)b * 32 + o) * NN + n];
        float sv = states[rw * 32 + o];
        res[q] = u * sv + (1.f - u) * cc;
      }
      float* o0 = out + (size_t)rw * 32 + p * 4;
      *(f32x4*)o0 = res;
      *(f32x4*)(o0 + OUTCOPY) = res;
    }
  }
}

// ---------------------------------------------------------------------------
// Fallback path kernels (ws too small): round-2 proven versions.
// ---------------------------------------------------------------------------
__global__ __launch_bounds__(256)
void pack_x1(const float* __restrict__ inputs, const float* __restrict__ states,
             unsigned short* __restrict__ H1) {
  int gid = blockIdx.x * 256 + threadIdx.x;
  int b = gid >> 10, n = gid & 1023;
  unsigned short* xb = H1 + (size_t)b * HB;
  xb[0 * NN + n] = f32_bf16(inputs[gid * 2 + 0]);
  xb[1 * NN + n] = f32_bf16(inputs[gid * 2 + 1]);
#pragma unroll
  for (int o = 0; o < 32; ++o) {
    int ch = 2 + o;
    xb[(ch >> 4) * SUBT + (ch & 15) * NN + n] = f32_bf16(states[gid * 32 + o]);
  }
#pragma unroll
  for (int ch = 34; ch < 48; ++ch)
    xb[2 * SUBT + (ch & 15) * NN + n] = 0;
}

__global__ __launch_bounds__(256)
void hop_slow(const float* __restrict__ Af32,
              const unsigned short* __restrict__ Hin,
              unsigned short* __restrict__ Hout,
              int si0, int si1, int so0, int so1) {
  __shared__ u32x4 lA4[1024];
  __shared__ u32x4 lX4[384];
  const int tid  = threadIdx.x;
  const int wave = tid >> 6, lane = tid & 63;
  const int l15  = lane & 15,  l4  = lane >> 4;
  const int mblk = blockIdx.x, b = blockIdx.y, s = blockIdx.z;
  const int slot_in  = s ? si1 : si0;
  const int slot_out = s ? so1 : so0;
  const unsigned short* Xb = Hin  + (size_t)b * HB + (size_t)slot_in  * 3 * SUBT;
  unsigned short*       Yb = Hout + (size_t)b * HB + (size_t)slot_out * 3 * SUBT;
  const size_t arow0 = ((size_t)(b * 2 + s) * NN + (size_t)mblk * 128) * NN;
  f32x4 acc[2][3];
#pragma unroll
  for (int mt = 0; mt < 2; ++mt)
#pragma unroll
    for (int nt = 0; nt < 3; ++nt)
#pragma unroll
      for (int e = 0; e < 4; ++e) acc[mt][nt][e] = 0.f;
  char* lAb = (char*)lA4;
  char* lXb = (char*)lX4;
  for (int kt = 0; kt < 16; ++kt) {
    const int kb0 = kt * 64;
    __syncthreads();
#pragma unroll
    for (int i = 0; i < 8; ++i) {
      int q = i * 256 + tid;
      int r = q >> 4, c = q & 15;
      float4 v = *(const float4*)(Af32 + arow0 + (size_t)r * NN + kb0 + c * 4);
      s16x4 o;
      o.x = (short)f32_bf16(v.x); o.y = (short)f32_bf16(v.y);
      o.z = (short)f32_bf16(v.z); o.w = (short)f32_bf16(v.w);
      *(s16x4*)(lAb + r * 128 + ((c * 8) ^ ((r & 7) << 4))) = o;
    }
    {
      int q = tid;
      int ct = q >> 7, rem = q & 127, ch = rem >> 3, c = rem & 7;
      const u32x4* src = (const u32x4*)(Xb + ct * SUBT + ch * NN + kb0 + c * 8);
      *(u32x4*)(lXb + ct * 2048 + ch * 128 + ((c ^ (ch & 7)) << 4)) = *src;
      if (tid < 128) {
        q = 256 + tid;
        ct = q >> 7; rem = q & 127; ch = rem >> 3; c = rem & 7;
        src = (const u32x4*)(Xb + ct * SUBT + ch * NN + kb0 + c * 8);
        *(u32x4*)(lXb + ct * 2048 + ch * 128 + ((c ^ (ch & 7)) << 4)) = *src;
      }
    }
    __syncthreads();
#pragma unroll
    for (int kb = 0; kb < 2; ++kb) {
      const int ko = kb * 64 + (l4 << 3);
      bf16x8 afr[2];
#pragma unroll
      for (int mt = 0; mt < 2; ++mt) {
        int row = wave * 32 + mt * 16 + l15;
        int sw  = (row & 7) << 4;
        s16x8 t;
        t.lo = *(const s16x4*)(lAb + row * 128 + (ko ^ sw));
        t.hi = *(const s16x4*)(lAb + row * 128 + ((ko + 32) ^ sw));
        afr[mt] = __builtin_bit_cast(bf16x8, t);
      }
#pragma unroll
      for (int nt = 0; nt < 3; ++nt) {
        const int swx = (l15 & 7) << 4;
        const char* bp = lXb + nt * 2048 + l15 * 128;
        s16x8 t;
        t.lo = *(const s16x4*)(bp + (ko ^ swx));
        t.hi = *(const s16x4*)(bp + ((ko + 32) ^ swx));
        bf16x8 bfr = __builtin_bit_cast(bf16x8, t);
#pragma unroll
        for (int mt = 0; mt < 2; ++mt)
          acc[mt][nt] = __builtin_amdgcn_mfma_f32_16x16x32_bf16(afr[mt], bfr, acc[mt][nt], 0, 0, 0);
      }
    }
  }
#pragma unroll
  for (int mt = 0; mt < 2; ++mt)
#pragma unroll
    for (int nt = 0; nt < 3; ++nt) {
      int ch   = nt * 16 + l15;
      int row0 = mblk * 128 + wave * 32 + mt * 16 + (l4 << 2);
      s16x4 o;
      o.x = (short)f32_bf16(acc[mt][nt][0]); o.y = (short)f32_bf16(acc[mt][nt][1]);
      o.z = (short)f32_bf16(acc[mt][nt][2]); o.w = (short)f32_bf16(acc[mt][nt][3]);
      *(s16x4*)(Yb + (size_t)ch * NN + row0) = o;
    }
}

__global__ __launch_bounds__(256)
void gate_ru_k(const unsigned short* __restrict__ H1,
               const float* __restrict__ W, const float* __restrict__ bias,
               const float* __restrict__ inputs, const float* __restrict__ states,
               unsigned short* __restrict__ H2, float* __restrict__ ubuf) {
  int gid = blockIdx.x * 256 + threadIdx.x;
  int b = gid >> 10, n = gid & 1023;
  const unsigned short* hb = H1 + (size_t)b * HB;
  float acc[64];
#pragma unroll
  for (int o = 0; o < 64; ++o) acc[o] = bias[o];
  for (int j = 0; j < 5; ++j) {
    const unsigned short* sb = hb + j * 3 * SUBT;
    for (int c = 0; c < 34; ++c) {
      float xv = bf16_f32(sb[(c >> 4) * SUBT + (c & 15) * NN + n]);
      const float* wr = W + (j * 34 + c) * 64;
#pragma unroll
      for (int o = 0; o < 64; ++o) acc[o] = fmaf(xv, wr[o], acc[o]);
    }
  }
  unsigned short* xb = H2 + (size_t)b * HB;
  xb[0 * NN + n] = f32_bf16(inputs[gid * 2 + 0]);
  xb[1 * NN + n] = f32_bf16(inputs[gid * 2 + 1]);
#pragma unroll
  for (int o = 0; o < 32; ++o) {
    float r = 1.f / (1.f + __expf(-acc[o]));
    float u = 1.f / (1.f + __expf(-acc[32 + o]));
    int ch = 2 + o;
    xb[(ch >> 4) * SUBT + (ch & 15) * NN + n] = f32_bf16(r * states[gid * 32 + o]);
    ubuf[((size_t)b * 32 + o) * NN + n] = u;
  }
#pragma unroll
  for (int ch = 34; ch < 48; ++ch)
    xb[2 * SUBT + (ch & 15) * NN + n] = 0;
}

__global__ __launch_bounds__(256)
void gate_c_k(const unsigned short* __restrict__ H2,
              const float* __restrict__ W, const float* __restrict__ bias,
              const float* __restrict__ states, const float* __restrict__ ubuf,
              float* __restrict__ out) {
  int gid = blockIdx.x * 256 + threadIdx.x;
  int b = gid >> 10, n = gid & 1023;
  const unsigned short* hb = H2 + (size_t)b * HB;
  float acc[32];
#pragma unroll
  for (int o = 0; o < 32; ++o) acc[o] = bias[o];
  for (int j = 0; j < 5; ++j) {
    const unsigned short* sb = hb + j * 3 * SUBT;
    for (int c = 0; c < 34; ++c) {
      float xv = bf16_f32(sb[(c >> 4) * SUBT + (c & 15) * NN + n]);
      const float* wr = W + (j * 34 + c) * 32;
#pragma unroll
      for (int o = 0; o < 32; ++o) acc[o] = fmaf(xv, wr[o], acc[o]);
    }
  }
  float res[32];
#pragma unroll
  for (int o = 0; o < 32; ++o) {
    float cc = tanhf(acc[o]);
    float u  = ubuf[((size_t)b * 32 + o) * NN + n];
    float sv = states[gid * 32 + o];
    res[o] = u * sv + (1.f - u) * cc;
  }
  float* o0 = out + (size_t)gid * 32;
#pragma unroll
  for (int q = 0; q < 8; ++q) {
    f32x4 v = { res[q * 4 + 0], res[q * 4 + 1], res[q * 4 + 2], res[q * 4 + 3] };
    *(f32x4*)(o0 + q * 4) = v;
    *(f32x4*)(o0 + OUTCOPY + q * 4) = v;
  }
}

// ---------------------------------------------------------------------------
extern "C" void kernel_launch(void* const* d_in, const int* in_sizes, int n_in,
                              void* d_out, int out_size, void* d_ws, size_t ws_size,
                              hipStream_t stream) {
  (void)in_sizes; (void)n_in; (void)out_size;
  const float* inputs   = (const float*)d_in[0];
  const float* supports = (const float*)d_in[1];
  const float* states   = (const float*)d_in[2];
  const float* W_ru     = (const float*)d_in[3];
  const float* b_ru     = (const float*)d_in[4];
  const float* W_c      = (const float*)d_in[5];
  const float* b_c      = (const float*)d_in[6];
  float* out = (float*)d_out;

  char* ws = (char*)d_ws;
  const size_t szA = 134217728;
  const size_t szH = 15728640;
  const size_t szU = 4194304;
  const size_t BAR_OFF = szA + 2 * szH + szU;
  const bool pathF = ws_size >= BAR_OFF + 256;

  if (pathF) {
    unsigned short* Apk = (unsigned short*)ws;
    unsigned short* H1  = (unsigned short*)(ws + szA);
    unsigned short* H2  = (unsigned short*)(ws + szA + szH);
    float*          ub  = (float*)(ws + szA + 2 * szH);
    unsigned*       bar = (unsigned*)(ws + BAR_OFF);
    hipMemsetAsync(bar, 0, 256, stream);
    dcgru_fused<<<dim3(256), dim3(512), 0, stream>>>(
        inputs, supports, states, W_ru, b_ru, W_c, b_c, out, Apk, H1, H2, ub, bar);
  } else {
    unsigned short* H1 = (unsigned short*)ws;
    unsigned short* H2 = (unsigned short*)(ws + szH);
    float*          ub = (float*)(ws + 2 * szH);
    dim3 sgrid(8, 32, 2), blk(256);
    pack_x1<<<dim3(128), blk, 0, stream>>>(inputs, states, H1);
    hop_slow<<<sgrid, blk, 0, stream>>>(supports, H1, H1, 0, 0, 1, 3);
    hop_slow<<<sgrid, blk, 0, stream>>>(supports, H1, H1, 1, 3, 2, 4);
    gate_ru_k<<<dim3(128), blk, 0, stream>>>(H1, W_ru, b_ru, inputs, states, H2, ub);
    hop_slow<<<sgrid, blk, 0, stream>>>(supports, H2, H2, 0, 0, 1, 3);
    hop_slow<<<sgrid, blk, 0, stream>>>(supports, H2, H2, 1, 3, 2, 4);
    gate_c_k<<<dim3(128), blk, 0, stream>>>(H2, W_c, b_c, states, ub, out);
  }
}

// Round 9
// 312.600 us; speedup vs baseline: 1.6487x; 1.6487x over previous
//
#include <hip/hip_runtime.h>

// ---------------------------------------------------------------------------
// DCGRU cell on MI355X — separate kernels, hop_v3 (counted-vmcnt ring).
// B=32, N=1024, C_IN=2, H=32, S=2, K=2, NUM_MAT=5, c_cat=34.
//
// ws (pathA): [Abf 128MB][H1 15MB][H2 15MB][ubuf 4MB]
// H buffer: per b: 5 slots x 3 ct x [16 ch][1024 n] bf16; ch 34..47 zero pad.
// Output: d_out = (outputs, outputs), each 1,048,576 fp32.
//
// hop_v3: Y = A @ X per (b,s). BM=256 rows/block (512 thr, 8 waves), BK=64.
// 3-buffer LDS ring (A 32KB + X 6KB = 38.9KB each, 114KB total -> 1 block/CU).
// Per K-step: WAIT vmcnt(5|4) -> s_barrier -> ISSUE(kt+2) -> COMPUTE(kt).
// 2 tiles always in flight via global_load_lds (no VGPR cost) => ~77KB/CU
// outstanding, no vmcnt(0) drain in the loop.
// ---------------------------------------------------------------------------

#define NN   1024
#define HB   245760
#define SUBT 16384
#define OUTCOPY 1048576
#define BUFSZ 38912   // 32768 (A) + 6144 (X)

typedef float  f32x4  __attribute__((ext_vector_type(4)));
typedef short  s16x4  __attribute__((ext_vector_type(4)));
typedef short  s16x8  __attribute__((ext_vector_type(8)));
typedef __bf16 bf16x8 __attribute__((ext_vector_type(8)));
typedef unsigned int u32x4 __attribute__((ext_vector_type(4)));

#define GAS __attribute__((address_space(1)))
#define LAS __attribute__((address_space(3)))

__device__ __forceinline__ unsigned short f32_bf16(float f) {
  unsigned int u = __float_as_uint(f);
  u += 0x7FFFu + ((u >> 16) & 1u);        // RNE
  return (unsigned short)(u >> 16);
}
__device__ __forceinline__ float bf16_f32(unsigned short h) {
  return __uint_as_float(((unsigned int)h) << 16);
}
__device__ __forceinline__ void gload_lds16(const unsigned short* g, void* l) {
  __builtin_amdgcn_global_load_lds((const GAS void*)g, (LAS void*)l, 16, 0, 0);
}

// ---------------------------------------------------------------------------
// supports fp32 -> bf16 (coalesced streaming)
// ---------------------------------------------------------------------------
__global__ __launch_bounds__(256)
void cvt_bf16(const float* __restrict__ src, unsigned short* __restrict__ dst, int n4) {
  int i = blockIdx.x * 256 + threadIdx.x;
  int stride = gridDim.x * 256;
  for (; i < n4; i += stride) {
    float4 v = ((const float4*)src)[i];
    s16x4 o;
    o.x = (short)f32_bf16(v.x);
    o.y = (short)f32_bf16(v.y);
    o.z = (short)f32_bf16(v.z);
    o.w = (short)f32_bf16(v.w);
    ((s16x4*)dst)[i] = o;
  }
}

// ---------------------------------------------------------------------------
// pack x1 = [inputs, states] into H1 slot 0 (XT layout)
// ---------------------------------------------------------------------------
__global__ __launch_bounds__(256)
void pack_x1(const float* __restrict__ inputs, const float* __restrict__ states,
             unsigned short* __restrict__ H1) {
  int gid = blockIdx.x * 256 + threadIdx.x;   // 0..32767
  int b = gid >> 10, n = gid & 1023;
  unsigned short* xb = H1 + (size_t)b * HB;
  xb[0 * NN + n] = f32_bf16(inputs[gid * 2 + 0]);
  xb[1 * NN + n] = f32_bf16(inputs[gid * 2 + 1]);
#pragma unroll
  for (int o = 0; o < 32; ++o) {
    int ch = 2 + o;
    xb[(ch >> 4) * SUBT + (ch & 15) * NN + n] = f32_bf16(states[gid * 32 + o]);
  }
#pragma unroll
  for (int ch = 34; ch < 48; ++ch)
    xb[2 * SUBT + (ch & 15) * NN + n] = 0;
}

// ---------------------------------------------------------------------------
// hop_v3
// ---------------------------------------------------------------------------
__global__ __launch_bounds__(512, 2)
void hop_v3(const unsigned short* __restrict__ Abf,
            const unsigned short* __restrict__ Hin,
            unsigned short* __restrict__ Hout,
            int si0, int si1, int so0, int so1) {
  __shared__ u32x4 ldsv[3 * 2432];   // 3 x 38912 B
  char* lds = (char*)ldsv;

  const int tid  = threadIdx.x;
  const int wave = tid >> 6, lane = tid & 63;
  const int l15  = lane & 15,  l4  = lane >> 4;
  const int mblk = blockIdx.x, b = blockIdx.y, s = blockIdx.z;
  const int slot_in  = s ? si1 : si0;
  const int slot_out = s ? so1 : so0;

  const unsigned short* Xb = Hin  + (size_t)b * HB + (size_t)slot_in  * 3 * SUBT;
  unsigned short*       Yb = Hout + (size_t)b * HB + (size_t)slot_out * 3 * SUBT;
  const size_t arow0 = ((size_t)(b * 2 + s) * NN + (size_t)mblk * 256) * NN;

  // issue one K-tile: A 2048 chunks (4/thread), X 384 chunks (tid<384: 1)
  auto ISSUE = [&](int kt, char* base) {
    const int kb0 = kt << 6;
#pragma unroll
    for (int i = 0; i < 4; ++i) {
      int q = i * 512 + tid;
      int r = q >> 3, cs = q & 7;
      gload_lds16(Abf + arow0 + (size_t)r * NN + kb0 + ((cs ^ (r & 7)) << 3),
                  base + (i * 512 + wave * 64) * 16);
    }
    if (tid < 384) {
      int ct = tid >> 7, rem = tid & 127, ch = rem >> 3, cs = rem & 7;
      gload_lds16(Xb + ct * SUBT + ch * NN + kb0 + ((cs ^ (ch & 7)) << 3),
                  base + 32768 + (wave * 64) * 16);
    }
  };

  f32x4 acc[2][3];
#pragma unroll
  for (int mt = 0; mt < 2; ++mt)
#pragma unroll
    for (int nt = 0; nt < 3; ++nt)
#pragma unroll
      for (int e = 0; e < 4; ++e) acc[mt][nt][e] = 0.f;

  const int swx = (l15 & 7) << 4;

  auto COMPUTE = [&](const char* bc) {
    const char* lXb = bc + 32768;
#pragma unroll
    for (int kb = 0; kb < 2; ++kb) {
      const int ko = kb * 64 + (l4 << 3);
      bf16x8 afr[2];
#pragma unroll
      for (int mt = 0; mt < 2; ++mt) {
        int row = wave * 32 + mt * 16 + l15;
        int sw  = (row & 7) << 4;
        s16x8 t;
        t.lo = *(const s16x4*)(bc + row * 128 + (ko ^ sw));
        t.hi = *(const s16x4*)(bc + row * 128 + ((ko + 32) ^ sw));
        afr[mt] = __builtin_bit_cast(bf16x8, t);
      }
#pragma unroll
      for (int nt = 0; nt < 3; ++nt) {
        const char* bp = lXb + (nt * 16 + l15) * 128;
        s16x8 t;
        t.lo = *(const s16x4*)(bp + (ko ^ swx));
        t.hi = *(const s16x4*)(bp + ((ko + 32) ^ swx));
        bf16x8 bfr = __builtin_bit_cast(bf16x8, t);
#pragma unroll
        for (int mt = 0; mt < 2; ++mt)
          acc[mt][nt] = __builtin_amdgcn_mfma_f32_16x16x32_bf16(afr[mt], bfr, acc[mt][nt], 0, 0, 0);
      }
    }
  };

  // wait until current tile retired (leave 1 tile = 5|4 loads in flight)
#define WB_MAIN() do {                                                   \
    if (wave < 6) asm volatile("s_waitcnt vmcnt(5)" ::: "memory");       \
    else          asm volatile("s_waitcnt vmcnt(4)" ::: "memory");       \
    __builtin_amdgcn_s_barrier();                                        \
    __builtin_amdgcn_sched_barrier(0);                                   \
  } while (0)
#define WB_LAST() do {                                                   \
    asm volatile("s_waitcnt vmcnt(0)" ::: "memory");                     \
    __builtin_amdgcn_s_barrier();                                        \
    __builtin_amdgcn_sched_barrier(0);                                   \
  } while (0)

  char* bA = lds;               // compute buffer (tile kt)
  char* bB = lds + BUFSZ;       // in-flight (tile kt+1)
  char* bC = lds + 2 * BUFSZ;   // issue target (tile kt+2)

  ISSUE(0, bA);
  ISSUE(1, bB);

#pragma unroll 1
  for (int kt = 0; kt < 14; ++kt) {
    WB_MAIN();                  // tile kt done; all waves past compute(kt-1)
    ISSUE(kt + 2, bC);          // safe: bC's old tile (kt-1) fully consumed
    COMPUTE(bA);
    char* t = bA; bA = bB; bB = bC; bC = t;
  }
  WB_MAIN();  COMPUTE(bA);      // kt=14 (tile 15 stays in flight)
  bA = bB;
  WB_LAST();  COMPUTE(bA);      // kt=15

#undef WB_MAIN
#undef WB_LAST

  // epilogue: D layout col(n)=l15, row(m)=l4*4+reg
#pragma unroll
  for (int mt = 0; mt < 2; ++mt) {
    const int row0 = mblk * 256 + wave * 32 + mt * 16 + (l4 << 2);
#pragma unroll
    for (int nt = 0; nt < 3; ++nt) {
      int ch = nt * 16 + l15;
      s16x4 o;
      o.x = (short)f32_bf16(acc[mt][nt][0]);
      o.y = (short)f32_bf16(acc[mt][nt][1]);
      o.z = (short)f32_bf16(acc[mt][nt][2]);
      o.w = (short)f32_bf16(acc[mt][nt][3]);
      *(s16x4*)(Yb + (size_t)ch * NN + row0) = o;
    }
  }
}

// ---------------------------------------------------------------------------
// hop_slow fallback (fp32 A, reg-staged) — proven round-2 version
// ---------------------------------------------------------------------------
__global__ __launch_bounds__(256)
void hop_slow(const float* __restrict__ Af32,
              const unsigned short* __restrict__ Hin,
              unsigned short* __restrict__ Hout,
              int si0, int si1, int so0, int so1) {
  __shared__ u32x4 lA4[1024];
  __shared__ u32x4 lX4[384];
  const int tid  = threadIdx.x;
  const int wave = tid >> 6, lane = tid & 63;
  const int l15  = lane & 15,  l4  = lane >> 4;
  const int mblk = blockIdx.x, b = blockIdx.y, s = blockIdx.z;
  const int slot_in  = s ? si1 : si0;
  const int slot_out = s ? so1 : so0;
  const unsigned short* Xb = Hin  + (size_t)b * HB + (size_t)slot_in  * 3 * SUBT;
  unsigned short*       Yb = Hout + (size_t)b * HB + (size_t)slot_out * 3 * SUBT;
  const size_t arow0 = ((size_t)(b * 2 + s) * NN + (size_t)mblk * 128) * NN;
  f32x4 acc[2][3];
#pragma unroll
  for (int mt = 0; mt < 2; ++mt)
#pragma unroll
    for (int nt = 0; nt < 3; ++nt)
#pragma unroll
      for (int e = 0; e < 4; ++e) acc[mt][nt][e] = 0.f;
  char* lAb = (char*)lA4;
  char* lXb = (char*)lX4;
  for (int kt = 0; kt < 16; ++kt) {
    const int kb0 = kt * 64;
    __syncthreads();
#pragma unroll
    for (int i = 0; i < 8; ++i) {
      int q = i * 256 + tid;
      int r = q >> 4, c = q & 15;
      float4 v = *(const float4*)(Af32 + arow0 + (size_t)r * NN + kb0 + c * 4);
      s16x4 o;
      o.x = (short)f32_bf16(v.x); o.y = (short)f32_bf16(v.y);
      o.z = (short)f32_bf16(v.z); o.w = (short)f32_bf16(v.w);
      *(s16x4*)(lAb + r * 128 + ((c * 8) ^ ((r & 7) << 4))) = o;
    }
    {
      int q = tid;
      int ct = q >> 7, rem = q & 127, ch = rem >> 3, c = rem & 7;
      const u32x4* src = (const u32x4*)(Xb + ct * SUBT + ch * NN + kb0 + c * 8);
      *(u32x4*)(lXb + ct * 2048 + ch * 128 + ((c ^ (ch & 7)) << 4)) = *src;
      if (tid < 128) {
        q = 256 + tid;
        ct = q >> 7; rem = q & 127; ch = rem >> 3; c = rem & 7;
        src = (const u32x4*)(Xb + ct * SUBT + ch * NN + kb0 + c * 8);
        *(u32x4*)(lXb + ct * 2048 + ch * 128 + ((c ^ (ch & 7)) << 4)) = *src;
      }
    }
    __syncthreads();
#pragma unroll
    for (int kb = 0; kb < 2; ++kb) {
      const int ko = kb * 64 + (l4 << 3);
      bf16x8 afr[2];
#pragma unroll
      for (int mt = 0; mt < 2; ++mt) {
        int row = wave * 32 + mt * 16 + l15;
        int sw  = (row & 7) << 4;
        s16x8 t;
        t.lo = *(const s16x4*)(lAb + row * 128 + (ko ^ sw));
        t.hi = *(const s16x4*)(lAb + row * 128 + ((ko + 32) ^ sw));
        afr[mt] = __builtin_bit_cast(bf16x8, t);
      }
#pragma unroll
      for (int nt = 0; nt < 3; ++nt) {
        const int swx = (l15 & 7) << 4;
        const char* bp = lXb + nt * 2048 + l15 * 128;
        s16x8 t;
        t.lo = *(const s16x4*)(bp + (ko ^ swx));
        t.hi = *(const s16x4*)(bp + ((ko + 32) ^ swx));
        bf16x8 bfr = __builtin_bit_cast(bf16x8, t);
#pragma unroll
        for (int mt = 0; mt < 2; ++mt)
          acc[mt][nt] = __builtin_amdgcn_mfma_f32_16x16x32_bf16(afr[mt], bfr, acc[mt][nt], 0, 0, 0);
      }
    }
  }
#pragma unroll
  for (int mt = 0; mt < 2; ++mt)
#pragma unroll
    for (int nt = 0; nt < 3; ++nt) {
      int ch   = nt * 16 + l15;
      int row0 = mblk * 128 + wave * 32 + mt * 16 + (l4 << 2);
      s16x4 o;
      o.x = (short)f32_bf16(acc[mt][nt][0]); o.y = (short)f32_bf16(acc[mt][nt][1]);
      o.z = (short)f32_bf16(acc[mt][nt][2]); o.w = (short)f32_bf16(acc[mt][nt][3]);
      *(s16x4*)(Yb + (size_t)ch * NN + row0) = o;
    }
}

// ---------------------------------------------------------------------------
// gate_ru: r_u = sigmoid(h1 @ W_ru + b_ru); H2 slot0 = [inputs, r*states]; u out
// ---------------------------------------------------------------------------
__global__ __launch_bounds__(256)
void gate_ru_k(const unsigned short* __restrict__ H1,
               const float* __restrict__ W, const float* __restrict__ bias,
               const float* __restrict__ inputs, const float* __restrict__ states,
               unsigned short* __restrict__ H2, float* __restrict__ ubuf) {
  int gid = blockIdx.x * 256 + threadIdx.x;
  int b = gid >> 10, n = gid & 1023;
  const unsigned short* hb = H1 + (size_t)b * HB;
  float acc[64];
#pragma unroll
  for (int o = 0; o < 64; ++o) acc[o] = bias[o];
  for (int j = 0; j < 5; ++j) {
    const unsigned short* sb = hb + j * 3 * SUBT;
    for (int c = 0; c < 34; ++c) {
      float xv = bf16_f32(sb[(c >> 4) * SUBT + (c & 15) * NN + n]);
      const float* wr = W + (j * 34 + c) * 64;
#pragma unroll
      for (int o = 0; o < 64; ++o) acc[o] = fmaf(xv, wr[o], acc[o]);
    }
  }
  unsigned short* xb = H2 + (size_t)b * HB;
  xb[0 * NN + n] = f32_bf16(inputs[gid * 2 + 0]);
  xb[1 * NN + n] = f32_bf16(inputs[gid * 2 + 1]);
#pragma unroll
  for (int o = 0; o < 32; ++o) {
    float r = 1.f / (1.f + __expf(-acc[o]));
    float u = 1.f / (1.f + __expf(-acc[32 + o]));
    int ch = 2 + o;
    xb[(ch >> 4) * SUBT + (ch & 15) * NN + n] = f32_bf16(r * states[gid * 32 + o]);
    ubuf[((size_t)b * 32 + o) * NN + n] = u;
  }
#pragma unroll
  for (int ch = 34; ch < 48; ++ch)
    xb[2 * SUBT + (ch & 15) * NN + n] = 0;
}

// ---------------------------------------------------------------------------
// gate_c: c = tanh(h2 @ W_c + b_c); out = u*states + (1-u)*c (written twice)
// ---------------------------------------------------------------------------
__global__ __launch_bounds__(256)
void gate_c_k(const unsigned short* __restrict__ H2,
              const float* __restrict__ W, const float* __restrict__ bias,
              const float* __restrict__ states, const float* __restrict__ ubuf,
              float* __restrict__ out) {
  int gid = blockIdx.x * 256 + threadIdx.x;
  int b = gid >> 10, n = gid & 1023;
  const unsigned short* hb = H2 + (size_t)b * HB;
  float acc[32];
#pragma unroll
  for (int o = 0; o < 32; ++o) acc[o] = bias[o];
  for (int j = 0; j < 5; ++j) {
    const unsigned short* sb = hb + j * 3 * SUBT;
    for (int c = 0; c < 34; ++c) {
      float xv = bf16_f32(sb[(c >> 4) * SUBT + (c & 15) * NN + n]);
      const float* wr = W + (j * 34 + c) * 32;
#pragma unroll
      for (int o = 0; o < 32; ++o) acc[o] = fmaf(xv, wr[o], acc[o]);
    }
  }
  float res[32];
#pragma unroll
  for (int o = 0; o < 32; ++o) {
    float cc = tanhf(acc[o]);
    float u  = ubuf[((size_t)b * 32 + o) * NN + n];
    float sv = states[gid * 32 + o];
    res[o] = u * sv + (1.f - u) * cc;
  }
  float* o0 = out + (size_t)gid * 32;
#pragma unroll
  for (int q = 0; q < 8; ++q) {
    f32x4 v = { res[q * 4 + 0], res[q * 4 + 1], res[q * 4 + 2], res[q * 4 + 3] };
    *(f32x4*)(o0 + q * 4) = v;
    *(f32x4*)(o0 + OUTCOPY + q * 4) = v;
  }
}

// ---------------------------------------------------------------------------
extern "C" void kernel_launch(void* const* d_in, const int* in_sizes, int n_in,
                              void* d_out, int out_size, void* d_ws, size_t ws_size,
                              hipStream_t stream) {
  (void)in_sizes; (void)n_in; (void)out_size;
  const float* inputs   = (const float*)d_in[0];
  const float* supports = (const float*)d_in[1];
  const float* states   = (const float*)d_in[2];
  const float* W_ru     = (const float*)d_in[3];
  const float* b_ru     = (const float*)d_in[4];
  const float* W_c      = (const float*)d_in[5];
  const float* b_c      = (const float*)d_in[6];
  float* out = (float*)d_out;

  char* ws = (char*)d_ws;
  const size_t szA = 134217728;
  const size_t szH = 15728640;
  const size_t szU = 4194304;
  const bool pathA = ws_size >= szA + 2 * szH + szU;
  const size_t off = pathA ? szA : 0;

  unsigned short* Abf = (unsigned short*)ws;
  unsigned short* H1  = (unsigned short*)(ws + off);
  unsigned short* H2  = (unsigned short*)(ws + off + szH);
  float*          ub  = (float*)(ws + off + 2 * szH);

  dim3 vgrid(4, 32, 2), sgrid(8, 32, 2), blk256(256), blk512(512);

  if (pathA)
    cvt_bf16<<<dim3(2048), blk256, 0, stream>>>(supports, Abf, 16777216);

  pack_x1<<<dim3(128), blk256, 0, stream>>>(inputs, states, H1);

  if (pathA) {
    hop_v3<<<vgrid, blk512, 0, stream>>>(Abf, H1, H1, 0, 0, 1, 3);
    hop_v3<<<vgrid, blk512, 0, stream>>>(Abf, H1, H1, 1, 3, 2, 4);
  } else {
    hop_slow<<<sgrid, blk256, 0, stream>>>(supports, H1, H1, 0, 0, 1, 3);
    hop_slow<<<sgrid, blk256, 0, stream>>>(supports, H1, H1, 1, 3, 2, 4);
  }

  gate_ru_k<<<dim3(128), blk256, 0, stream>>>(H1, W_ru, b_ru, inputs, states, H2, ub);

  if (pathA) {
    hop_v3<<<vgrid, blk512, 0, stream>>>(Abf, H2, H2, 0, 0, 1, 3);
    hop_v3<<<vgrid, blk512, 0, stream>>>(Abf, H2, H2, 1, 3, 2, 4);
  } else {
    hop_slow<<<sgrid, blk256, 0, stream>>>(supports, H2, H2, 0, 0, 1, 3);
    hop_slow<<<sgrid, blk256, 0, stream>>>(supports, H2, H2, 1, 3, 2, 4);
  }

  gate_c_k<<<dim3(128), blk256, 0, stream>>>(H2, W_c, b_c, states, ub, out);
}